// Round 11
// baseline (14830.292 us; speedup 1.0000x reference)
//
#include <hip/hip_runtime.h>

// Farthest point sampling, B=32, N=32768, npoint=4096.
// R11 = R10 with the register-residency fix:
//  - amdgpu_waves_per_eu(4,4): pin occupancy target to exactly 4 waves/EU
//    (the max a 1024-thread block allows anyway at 128KB LDS -> 1 block/CU).
//    Dynamic LDS made the compiler assume LDS=0 and target 8 waves/EU ->
//    64-VGPR cap -> px/py/dist lived in AGPRs with v_accvgpr copy traffic
//    (R7/R10: VGPR_Count=64). Budget at 4 waves/EU = 512 -> ~112-float live
//    set fits in arch VGPRs.
//  - quad ownership g = c*4096 + 4*tid + j: pz reads via ds_read_b128
//    (8 LDS issues/step, full-BW pattern).
//  - final reduce (R10, proven): 16 wave leaders LDS-atomicMax packed key
//    (f32bits(dist)<<32 | ~idx) into slot[k&1]; B1; read; reset other slot;
//    B2. Ties -> smaller global index (numpy first-occurrence).
// PASSING arithmetic (R6, bit-exact): d = fmaf(dz,dz, fmaf(dx,dx, dy*dy)),
// contract(off), fminf chain, ascending-index strict-> argmax.
// Output float32: [B*NPOINT] idx, [B*NPOINT*3] coords.

#define BATCH  32
#define NPTS   32768
#define NPOINT 4096
#define NT     1024
#define NC     8             // chunks of 4: 32 points per thread
#define SMEM_BYTES (NPTS * 4 + 32)

__global__ __launch_bounds__(NT)
__attribute__((amdgpu_waves_per_eu(4, 4)))
void fps_kernel(
    const float* __restrict__ xyz,   // [B, N, 3] float32
    float* __restrict__ out_idx,     // [B, NPOINT]
    float* __restrict__ out_xyz)     // [B, NPOINT, 3]
{
#pragma clang fp contract(off)
    extern __shared__ char smem[];
    float* pz_lds = (float*)smem;                                // NPTS floats
    unsigned long long* s_key = (unsigned long long*)(smem + NPTS * 4); // [2]

    const int b   = blockIdx.x;
    const int tid = threadIdx.x;
    const float* base = xyz + (size_t)b * NPTS * 3;

    float px[NC * 4], py[NC * 4], dist[NC * 4];
#pragma unroll
    for (int c = 0; c < NC; ++c) {
#pragma unroll
        for (int j = 0; j < 4; ++j) {
            const int i = c * 4 + j;
            const int g = c * 4096 + 4 * tid + j;
            px[i] = base[g * 3 + 0];
            py[i] = base[g * 3 + 1];
            pz_lds[g] = base[g * 3 + 2];
            dist[i] = 1e10f;
        }
    }
    if (tid == 0) { s_key[0] = 0ull; s_key[1] = 0ull; }
    __syncthreads();                       // pz_lds + slots ready

    int w = 1;   // RAN=False seed

    for (int k = 0; k < NPOINT; ++k) {
        // Broadcast centroid from global (same addr across lanes, L2-hot).
        const float cx = base[w * 3 + 0];
        const float cy = base[w * 3 + 1];
        const float cz = base[w * 3 + 2];
        if (tid == 0) {
            out_idx[(size_t)b * NPOINT + k] = (float)w;
            float* o = out_xyz + ((size_t)b * NPOINT + k) * 3;
            o[0] = cx; o[1] = cy; o[2] = cz;
        }

        // Distance update + first-occurrence argmax (indices ascend per
        // thread: g = c*4096 + 4*tid + j with c,j ascending).
        float best = -1.0f;
        int   bi   = 0x7fffffff;
#pragma unroll
        for (int c = 0; c < NC; ++c) {
            const float4 pz4 =
                *(const float4*)&pz_lds[c * 4096 + 4 * tid];  // ds_read_b128
            const float pzv[4] = { pz4.x, pz4.y, pz4.z, pz4.w };
#pragma unroll
            for (int j = 0; j < 4; ++j) {
                const int i = c * 4 + j;
                const float dx = px[i] - cx;
                const float dy = py[i] - cy;
                const float dz = pzv[j] - cz;
                const float d  = fmaf(dz, dz, fmaf(dx, dx, dy * dy));
                const float nd = fminf(dist[i], d);
                dist[i] = nd;
                if (nd > best) { best = nd; bi = c * 4096 + 4 * tid + j; }
            }
        }

        // Wave (64-lane) butterfly argmax; ties -> smaller index.
#pragma unroll
        for (int off = 1; off < 64; off <<= 1) {
            const float ov = __shfl_xor(best, off, 64);
            const int   oi = __shfl_xor(bi,   off, 64);
            if (ov > best || (ov == best && oi < bi)) { best = ov; bi = oi; }
        }

        // 16 wave leaders -> LDS atomicMax on packed key, slot k&1.
        const int p = k & 1;
        if ((tid & 63) == 0) {
            const unsigned long long myk =
                ((unsigned long long)__float_as_uint(best) << 32) |
                (unsigned int)(~bi);
            atomicMax(&s_key[p], myk);
        }
        __syncthreads();                   // B1: winner key published
        const unsigned long long kk = s_key[p];
        if (tid == 0) s_key[p ^ 1] = 0ull; // reset other slot (used at k+1)
        __syncthreads();                   // B2: reset ordered before k+1 max
        w = (int)(~(unsigned int)kk);      // low word = ~idx
    }
}

extern "C" void kernel_launch(void* const* d_in, const int* in_sizes, int n_in,
                              void* d_out, int out_size, void* d_ws, size_t ws_size,
                              hipStream_t stream) {
    const float* xyz = (const float*)d_in[0];
    float* out = (float*)d_out;
    float* out_idx = out;                              // B*NPOINT floats
    float* out_xyz = out + (size_t)BATCH * NPOINT;     // B*NPOINT*3 floats

    // Opt into >64KB dynamic LDS (runtime call, not captured by graphs).
    (void)hipFuncSetAttribute((const void*)fps_kernel,
                              hipFuncAttributeMaxDynamicSharedMemorySize,
                              SMEM_BYTES);

    fps_kernel<<<BATCH, NT, SMEM_BYTES, stream>>>(xyz, out_idx, out_xyz);
}

// Round 12
// 12788.367 us; speedup vs baseline: 1.1597x; 1.1597x over previous
//
#include <hip/hip_runtime.h>

// Farthest point sampling, B=32, N=32768, npoint=4096.
// R12: defeat the AGPR-spill by making LDS static & small:
//  - STATIC __shared__ pzlo[14336] (56KB, chunks c<7); chunks c>=7 keep pz
//    in 18 registers. Compiler now SEES the LDS size -> occupancy target
//    2 blocks/CU (8 waves/EU) -> 256-VGPR budget -> px/py/dist/pzr
//    (~130 floats) allocated in ARCH VGPRs, no v_accvgpr copy traffic.
//    (R7-R11: dynamic extern __shared__ hid LDS -> compiler capped arch
//    VGPRs at 64 and AGPR-spilled the arrays; VGPR_Count=64 every round.)
//  - ONE barrier/step: 3-slot rotation. Leaders atomicMax packed key
//    (f32bits(dist)<<32 | ~idx) into s_key[k%3]; barrier; all read winner;
//    tid0 resets s_key[(k+2)%3] (next use is step k+2; the intervening
//    barrier orders reset before that step's atomicMax). Ties -> smaller
//    global index (numpy first-occurrence).
//  - pair ownership g = c*2048 + 2*tid + j (R10's proven ds_read_b64).
// PASSING arithmetic (R6, bit-exact): d = fmaf(dz,dz, fmaf(dx,dx, dy*dy)),
// contract(off), fminf chain, ascending-index strict-> argmax.
// Output float32: [B*NPOINT] idx, [B*NPOINT*3] coords.

#define BATCH  32
#define NPTS   32768
#define NPOINT 4096
#define NT     1024
#define NCT    16            // total chunks of 2: 32 points per thread
#define NCL    7             // chunks with pz in LDS (14336 pts, 56KB)
#define NCR    (NCT - NCL)   // chunks with pz in registers (18 floats)

__global__ __launch_bounds__(NT, 1) void fps_kernel(
    const float* __restrict__ xyz,   // [B, N, 3] float32
    float* __restrict__ out_idx,     // [B, NPOINT]
    float* __restrict__ out_xyz)     // [B, NPOINT, 3]
{
#pragma clang fp contract(off)
    __shared__ float pzlo[NCL * 2048];          // 56 KB static
    __shared__ unsigned long long s_key[3];

    const int b   = blockIdx.x;
    const int tid = threadIdx.x;
    const float* base = xyz + (size_t)b * NPTS * 3;

    float px[NCT * 2], py[NCT * 2], dist[NCT * 2];
    float pzr[NCR * 2];
#pragma unroll
    for (int c = 0; c < NCT; ++c) {
#pragma unroll
        for (int j = 0; j < 2; ++j) {
            const int i = c * 2 + j;
            const int g = c * 2048 + 2 * tid + j;
            px[i] = base[g * 3 + 0];
            py[i] = base[g * 3 + 1];
            const float z = base[g * 3 + 2];
            if (c < NCL) pzlo[g] = z;
            else         pzr[(c - NCL) * 2 + j] = z;
            dist[i] = 1e10f;
        }
    }
    if (tid == 0) { s_key[0] = 0ull; s_key[1] = 0ull; s_key[2] = 0ull; }
    __syncthreads();                       // pzlo + slots ready

    int w = 1;   // RAN=False seed
    int p = 0;   // rotating slot index k%3

    for (int k = 0; k < NPOINT; ++k) {
        // Broadcast centroid from global (same addr across lanes, L2-hot).
        const float cx = base[w * 3 + 0];
        const float cy = base[w * 3 + 1];
        const float cz = base[w * 3 + 2];
        if (tid == 0) {
            out_idx[(size_t)b * NPOINT + k] = (float)w;
            float* o = out_xyz + ((size_t)b * NPOINT + k) * 3;
            o[0] = cx; o[1] = cy; o[2] = cz;
        }

        // Distance update + first-occurrence argmax (per-thread indices
        // ascend: c, j ascending -> strict > keeps the first max).
        float best = -1.0f;
        int   bi   = 0x7fffffff;
#pragma unroll
        for (int c = 0; c < NCT; ++c) {
            float pz0, pz1;
            if (c < NCL) {
                const float2 zz = *(const float2*)&pzlo[c * 2048 + 2 * tid];
                pz0 = zz.x; pz1 = zz.y;
            } else {
                pz0 = pzr[(c - NCL) * 2 + 0];
                pz1 = pzr[(c - NCL) * 2 + 1];
            }
#pragma unroll
            for (int j = 0; j < 2; ++j) {
                const int i = c * 2 + j;
                const float dx = px[i] - cx;
                const float dy = py[i] - cy;
                const float dz = (j == 0 ? pz0 : pz1) - cz;
                const float d  = fmaf(dz, dz, fmaf(dx, dx, dy * dy));
                const float nd = fminf(dist[i], d);
                dist[i] = nd;
                if (nd > best) { best = nd; bi = c * 2048 + 2 * tid + j; }
            }
        }

        // Wave (64-lane) butterfly argmax; ties -> smaller index.
#pragma unroll
        for (int off = 1; off < 64; off <<= 1) {
            const float ov = __shfl_xor(best, off, 64);
            const int   oi = __shfl_xor(bi,   off, 64);
            if (ov > best || (ov == best && oi < bi)) { best = ov; bi = oi; }
        }

        // 16 wave leaders -> LDS atomicMax on packed key, slot p = k%3.
        if ((tid & 63) == 0) {
            const unsigned long long myk =
                ((unsigned long long)__float_as_uint(best) << 32) |
                (unsigned int)(~bi);
            atomicMax(&s_key[p], myk);
        }
        __syncthreads();                   // winner published
        const unsigned long long kk = s_key[p];
        // Reset the slot for step k+2 (barrier of step k+1 orders this
        // write before step k+2's atomicMax; readers of slot (k+2)%3
        // finished at step k-1, before this step's barrier).
        const int pn2 = (p >= 1) ? (p - 1) : 2;   // (k+2)%3
        if (tid == 0) s_key[pn2] = 0ull;
        w = (int)(~(unsigned int)kk);      // low word = ~idx
        p = (p == 2) ? 0 : (p + 1);
    }
}

extern "C" void kernel_launch(void* const* d_in, const int* in_sizes, int n_in,
                              void* d_out, int out_size, void* d_ws, size_t ws_size,
                              hipStream_t stream) {
    const float* xyz = (const float*)d_in[0];
    float* out = (float*)d_out;
    float* out_idx = out;                              // B*NPOINT floats
    float* out_xyz = out + (size_t)BATCH * NPOINT;     // B*NPOINT*3 floats

    fps_kernel<<<BATCH, NT, 0, stream>>>(xyz, out_idx, out_xyz);
}

// Round 13
// 12257.832 us; speedup vs baseline: 1.2099x; 1.0433x over previous
//
#include <hip/hip_runtime.h>

// Farthest point sampling, B=32, N=32768, npoint=4096.
// R13: attack VALU issue count (we are issue-bound: 95% per-active-CU
// VALUBusy, ~880 inst/wave/step vs ~360 essential).
//  - NT=512 (64 pts/thread), amdgpu_waves_per_eu(2,2): 1 block/CU, 2
//    waves/SIMD -> per-wave register budget 256+; x/y/dist (float2[32]
//    each) can be ARCH-VGPR resident, killing v_accvgpr copy traffic
//    (R7-R12 were stuck at VGPR_Count=64 = max-occupancy default budget).
//  - packed f32: subs/mul/fma on float2 lower to v_pk_add/v_pk_mul/
//    v_pk_fma_f32 (IEEE-identical per component -> bit-exact).
//  - argmax tracks a 6-bit local chunk id (inline-const cndmask, no
//    per-point index add); global index reconstructed once per step.
//    Local id ascends with global index -> first-occurrence preserved.
//  - z in dynamic LDS (128KB), ds_read_b64 pairs; 3-slot LDS atomicMax
//    reduce (R12, proven); centroid via global broadcast load.
// PASSING arithmetic (R6, bit-exact): d = fmaf(dz,dz, fmaf(dx,dx, dy*dy)),
// contract(off), fminf chain, ascending-index strict-> argmax.
// Output float32: [B*NPOINT] idx, [B*NPOINT*3] coords.

#define BATCH  32
#define NPTS   32768
#define NPOINT 4096
#define NT     512
#define NCH    32            // chunks of 2: 64 points per thread
#define SMEM_BYTES (NPTS * 4 + 32)

typedef float f32x2 __attribute__((ext_vector_type(2)));

#if __has_builtin(__builtin_elementwise_fma)
#define VFMA(a, b, c) __builtin_elementwise_fma((a), (b), (c))
#else
static __device__ inline f32x2 VFMA(f32x2 a, f32x2 b, f32x2 c) {
    f32x2 r; r[0] = fmaf(a[0], b[0], c[0]); r[1] = fmaf(a[1], b[1], c[1]);
    return r;
}
#endif

__global__ __launch_bounds__(NT)
__attribute__((amdgpu_waves_per_eu(2, 2)))
void fps_kernel(
    const float* __restrict__ xyz,   // [B, N, 3] float32
    float* __restrict__ out_idx,     // [B, NPOINT]
    float* __restrict__ out_xyz)     // [B, NPOINT, 3]
{
#pragma clang fp contract(off)
    extern __shared__ char smem[];
    float* pz_lds = (float*)smem;                                // NPTS floats
    unsigned long long* s_key = (unsigned long long*)(smem + NPTS * 4); // [3]

    const int b   = blockIdx.x;
    const int tid = threadIdx.x;
    const float* base = xyz + (size_t)b * NPTS * 3;

    f32x2 px2[NCH], py2[NCH], dist2[NCH];
#pragma unroll
    for (int c = 0; c < NCH; ++c) {
#pragma unroll
        for (int j = 0; j < 2; ++j) {
            const int g = c * 1024 + 2 * tid + j;
            px2[c][j] = base[g * 3 + 0];
            py2[c][j] = base[g * 3 + 1];
            pz_lds[g] = base[g * 3 + 2];
            dist2[c][j] = 1e10f;
        }
    }
    if (tid == 0) { s_key[0] = 0ull; s_key[1] = 0ull; s_key[2] = 0ull; }
    __syncthreads();                       // pz_lds + slots ready

    int w = 1;   // RAN=False seed
    int p = 0;   // rotating slot index k%3

    for (int k = 0; k < NPOINT; ++k) {
        // Broadcast centroid from global (same addr across lanes, L2-hot).
        const float cx = base[w * 3 + 0];
        const float cy = base[w * 3 + 1];
        const float cz = base[w * 3 + 2];
        if (tid == 0) {
            out_idx[(size_t)b * NPOINT + k] = (float)w;
            float* o = out_xyz + ((size_t)b * NPOINT + k) * 3;
            o[0] = cx; o[1] = cy; o[2] = cz;
        }
        const f32x2 cx2 = { cx, cx };
        const f32x2 cy2 = { cy, cy };
        const f32x2 cz2 = { cz, cz };

        // Distance update + first-occurrence argmax over 64 points.
        // Local candidate id lc = 2c+j (6 bits) ascends with global index
        // g = c*1024 + 2*tid + j -> strict > keeps numpy first-occurrence.
        float best = -1.0f;
        int   lc   = 127;   // invalid-high; any real candidate beats via >
#pragma unroll
        for (int c = 0; c < NCH; ++c) {
            const f32x2 zz = *(const f32x2*)&pz_lds[c * 1024 + 2 * tid];
            const f32x2 dx2 = px2[c] - cx2;          // v_pk_add (neg)
            const f32x2 dy2 = py2[c] - cy2;
            const f32x2 dz2 = zz     - cz2;
            const f32x2 d2  = VFMA(dz2, dz2, VFMA(dx2, dx2, dy2 * dy2));
#pragma unroll
            for (int j = 0; j < 2; ++j) {
                const float nd = fminf(dist2[c][j], d2[j]);
                dist2[c][j] = nd;
                if (nd > best) { best = nd; lc = 2 * c + j; }
            }
        }
        // Reconstruct global index once: g = (lc>>1)*1024 + 2*tid + (lc&1).
        int bi = (lc >> 1) * 1024 + 2 * tid + (lc & 1);

        // Wave (64-lane) butterfly argmax; ties -> smaller index.
#pragma unroll
        for (int off = 1; off < 64; off <<= 1) {
            const float ov = __shfl_xor(best, off, 64);
            const int   oi = __shfl_xor(bi,   off, 64);
            if (ov > best || (ov == best && oi < bi)) { best = ov; bi = oi; }
        }

        // 8 wave leaders -> LDS atomicMax on packed key, slot p = k%3.
        if ((tid & 63) == 0) {
            const unsigned long long myk =
                ((unsigned long long)__float_as_uint(best) << 32) |
                (unsigned int)(~bi);
            atomicMax(&s_key[p], myk);
        }
        __syncthreads();                   // winner published
        const unsigned long long kk = s_key[p];
        // Reset the slot for step k+2 (next step's barrier orders this
        // write before step k+2's atomicMax; readers of that slot finished
        // at step k-1, before this step's barrier).
        const int pn2 = (p >= 1) ? (p - 1) : 2;   // (k+2)%3
        if (tid == 0) s_key[pn2] = 0ull;
        w = (int)(~(unsigned int)kk);      // low word = ~idx
        p = (p == 2) ? 0 : (p + 1);
    }
}

extern "C" void kernel_launch(void* const* d_in, const int* in_sizes, int n_in,
                              void* d_out, int out_size, void* d_ws, size_t ws_size,
                              hipStream_t stream) {
    const float* xyz = (const float*)d_in[0];
    float* out = (float*)d_out;
    float* out_idx = out;                              // B*NPOINT floats
    float* out_xyz = out + (size_t)BATCH * NPOINT;     // B*NPOINT*3 floats

    // Opt into >64KB dynamic LDS (runtime call, not captured by graphs).
    (void)hipFuncSetAttribute((const void*)fps_kernel,
                              hipFuncAttributeMaxDynamicSharedMemorySize,
                              SMEM_BYTES);

    fps_kernel<<<BATCH, NT, SMEM_BYTES, stream>>>(xyz, out_idx, out_xyz);
}